// Round 11
// baseline (169.177 us; speedup 1.0000x reference)
//
#include <hip/hip_runtime.h>

#define BB 8
#define CCH 19
#define HH 512
#define WW 1024
#define HW (HH * WW)          // 524288
#define NPIX (BB * HW)        // 4194304
#define CHW (CCH * HW)
#define N4 (NPIX / 4)         // 1048576
#define GRID2 1024

#define FIX_SCALE 17179869184.0   // 2^34

__device__ __forceinline__ unsigned fkey(float x) {
    unsigned u = __float_as_uint(x);
    return (u & 0x80000000u) ? ~u : (u | 0x80000000u);
}
// two's-complement fixed point; |total| < 4.2M * 20 * 2^34 < 2^63
__device__ __forceinline__ unsigned long long fix64(float x) {
    return (unsigned long long)(long long)((double)x * FIX_SCALE);
}
__device__ __forceinline__ unsigned agent_load_u32(const unsigned* p) {
    return __hip_atomic_load(p, __ATOMIC_RELAXED, __HIP_MEMORY_SCOPE_AGENT);
}
__device__ __forceinline__ unsigned long long agent_load_u64(const unsigned long long* p) {
    return __hip_atomic_load(p, __ATOMIC_RELAXED, __HIP_MEMORY_SCOPE_AGENT);
}

// ---- pass 1: per-pixel CE (float4) + fused 11-bit count histogram ----
// GOLDEN KERNEL - DO NOT TOUCH. Byte-identical to round 10 (118us total).
// No pow(), no scan tail, no ticket: any fat head/tail fused here makes the
// scheduler compress the loop to VGPR~60 -> ~10 loads in flight -> 290us
// (rounds 5-9). Clean: all 19 channel loads in flight -> ~85us.
__global__ __launch_bounds__(256) void k_loss_hist(const float* __restrict__ pred,
                                                   const int* __restrict__ target,
                                                   float* __restrict__ loss,
                                                   unsigned* __restrict__ hist) {
    __shared__ unsigned h[2048];
    for (int i = threadIdx.x; i < 2048; i += 256) h[i] = 0;
    __syncthreads();

    int stride = gridDim.x * 256;
    for (int i4 = blockIdx.x * 256 + threadIdx.x; i4 < N4; i4 += stride) {
        int p0 = i4 << 2;
        int b = p0 >> 19;           // / HW
        int hw = p0 & (HW - 1);
        const float* base = pred + (size_t)b * CHW + hw;

        float4 v[CCH];
#pragma unroll
        for (int c = 0; c < CCH; ++c)
            v[c] = *reinterpret_cast<const float4*>(base + (size_t)c * HW);
        int4 tg = *reinterpret_cast<const int4*>(target + p0);

        float4 mx = v[0];
#pragma unroll
        for (int c = 1; c < CCH; ++c) {
            mx.x = fmaxf(mx.x, v[c].x);
            mx.y = fmaxf(mx.y, v[c].y);
            mx.z = fmaxf(mx.z, v[c].z);
            mx.w = fmaxf(mx.w, v[c].w);
        }
        float4 s = make_float4(0.f, 0.f, 0.f, 0.f);
        float4 xt = make_float4(0.f, 0.f, 0.f, 0.f);
#pragma unroll
        for (int c = 0; c < CCH; ++c) {
            s.x += __expf(v[c].x - mx.x);
            s.y += __expf(v[c].y - mx.y);
            s.z += __expf(v[c].z - mx.z);
            s.w += __expf(v[c].w - mx.w);
            xt.x = (tg.x == c) ? v[c].x : xt.x;
            xt.y = (tg.y == c) ? v[c].y : xt.y;
            xt.z = (tg.z == c) ? v[c].z : xt.z;
            xt.w = (tg.w == c) ? v[c].w : xt.w;
        }
        float4 o;
        o.x = __logf(s.x) + mx.x - xt.x;
        o.y = __logf(s.y) + mx.y - xt.y;
        o.z = __logf(s.z) + mx.z - xt.z;
        o.w = __logf(s.w) + mx.w - xt.w;
        *reinterpret_cast<float4*>(loss + p0) = o;

        atomicAdd(&h[fkey(o.x) >> 21], 1u);
        atomicAdd(&h[fkey(o.y) >> 21], 1u);
        atomicAdd(&h[fkey(o.z) >> 21], 1u);
        atomicAdd(&h[fkey(o.w) >> 21], 1u);
    }
    __syncthreads();
    for (int i = threadIdx.x; i < 2048; i += 256) {
        unsigned c = h[i];
        if (c) atomicAdd(&hist[i], c);
    }
}

// ---- pass 2 (fused): head = per-block redundant scan of h1 -> b1,k1;
//      body = classify loss elements; tail = last block finalizes ----
__global__ __launch_bounds__(256) void k_hist2_final(
    const float* __restrict__ loss, const int* __restrict__ step_p,
    const unsigned* __restrict__ h1,
    unsigned* __restrict__ h2g, unsigned long long* __restrict__ bs2g,
    unsigned long long* __restrict__ aboveSum, unsigned* __restrict__ aboveCnt,
    unsigned* __restrict__ ticket, float* __restrict__ out)
{
    __shared__ unsigned h[2048];
    __shared__ unsigned long long bs[2048];
    __shared__ unsigned chunk[256];
    __shared__ unsigned b_sh, k_sh, isLast;
    __shared__ unsigned long long wsum[4];
    __shared__ unsigned wcnt[4];
    const int tid = threadIdx.x, bid = blockIdx.x;

    for (int i = tid; i < 2048; i += 256) { h[i] = 0u; bs[i] = 0ull; }

    // ---- head: every block redundantly suffix-scans h1 (8 KB, L2-hot) ----
    unsigned num;
    {
        int s = step_p[0];
        double m = pow(0.99998, (double)s);
        double f = m > 0.15 ? m : 0.15;
        num = (unsigned)(0.15 * (double)BB * (double)HH * (double)WW * f);
    }
    {
        unsigned local[8];
        unsigned lsum = 0;
#pragma unroll
        for (int j = 0; j < 8; ++j) { local[j] = h1[tid * 8 + j]; lsum += local[j]; }
        chunk[tid] = lsum;
        __syncthreads();
        for (int off = 1; off < 256; off <<= 1) {
            unsigned add = (tid + off < 256) ? chunk[tid + off] : 0u;
            __syncthreads();
            chunk[tid] += add;
            __syncthreads();
        }
        unsigned cum = (tid < 255) ? chunk[tid + 1] : 0u;  // strictly above my chunk
#pragma unroll
        for (int j = 7; j >= 0; --j) {
            unsigned c = local[j];
            if (num > cum && num <= cum + c) {
                b_sh = (unsigned)(tid * 8 + j);
                k_sh = num - cum;
            }
            cum += c;
        }
    }
    __syncthreads();
    const unsigned b1 = b_sh;
    const unsigned k1 = k_sh;

    // ---- body: above-b1 -> register sum/count; in-b1 -> 11-bit LDS hist ----
    unsigned long long asum = 0ull;
    unsigned acnt = 0;
    int stride = gridDim.x * 256;
    for (int i4 = bid * 256 + tid; i4 < N4; i4 += stride) {
        float4 v = reinterpret_cast<const float4*>(loss)[i4];
        unsigned u, hi;
        u = fkey(v.x); hi = u >> 21;
        if (hi > b1) { asum += fix64(v.x); acnt++; }
        else if (hi == b1) { unsigned idx = (u >> 10) & 2047u; atomicAdd(&h[idx], 1u); atomicAdd(&bs[idx], fix64(v.x)); }
        u = fkey(v.y); hi = u >> 21;
        if (hi > b1) { asum += fix64(v.y); acnt++; }
        else if (hi == b1) { unsigned idx = (u >> 10) & 2047u; atomicAdd(&h[idx], 1u); atomicAdd(&bs[idx], fix64(v.y)); }
        u = fkey(v.z); hi = u >> 21;
        if (hi > b1) { asum += fix64(v.z); acnt++; }
        else if (hi == b1) { unsigned idx = (u >> 10) & 2047u; atomicAdd(&h[idx], 1u); atomicAdd(&bs[idx], fix64(v.z)); }
        u = fkey(v.w); hi = u >> 21;
        if (hi > b1) { asum += fix64(v.w); acnt++; }
        else if (hi == b1) { unsigned idx = (u >> 10) & 2047u; atomicAdd(&h[idx], 1u); atomicAdd(&bs[idx], fix64(v.w)); }
    }
    // deterministic integer block reduction of the "above" partials
#pragma unroll
    for (int off = 32; off >= 1; off >>= 1) {
        asum += __shfl_down(asum, off);
        acnt += __shfl_down(acnt, off);
    }
    {
        const int wid = tid >> 6, lane = tid & 63;
        if (lane == 0) { wsum[wid] = asum; wcnt[wid] = acnt; }
    }
    __syncthreads();
    if (tid == 0) {
        unsigned long long ts = wsum[0] + wsum[1] + wsum[2] + wsum[3];
        unsigned tc = wcnt[0] + wcnt[1] + wcnt[2] + wcnt[3];
        if (ts) atomicAdd(aboveSum, ts);
        if (tc) atomicAdd(aboveCnt, tc);
    }
    __syncthreads();
    for (int i = tid; i < 2048; i += 256) {
        unsigned c = h[i];
        if (c) { atomicAdd(&h2g[i], c); atomicAdd(&bs2g[i], bs[i]); }
    }
    __threadfence();
    if (tid == 0) isLast = (atomicAdd(ticket, 1u) == (unsigned)(gridDim.x - 1)) ? 1u : 0u;
    __syncthreads();
    if (!isLast) return;

    // ---- tail: last block scans h2, includes bins >= b2, adds above ----
    if (tid == 0) b_sh = 0u;   // fallback: whole b1 bin
    unsigned local2[8];
    unsigned lsum2 = 0;
#pragma unroll
    for (int j = 0; j < 8; ++j) { local2[j] = agent_load_u32(&h2g[tid * 8 + j]); lsum2 += local2[j]; }
    chunk[tid] = lsum2;
    __syncthreads();
    for (int off = 1; off < 256; off <<= 1) {
        unsigned add = (tid + off < 256) ? chunk[tid + off] : 0u;
        __syncthreads();
        chunk[tid] += add;
        __syncthreads();
    }
    {
        unsigned cum = (tid < 255) ? chunk[tid + 1] : 0u;
#pragma unroll
        for (int j = 7; j >= 0; --j) {
            unsigned c = local2[j];
            if (k1 > cum && k1 <= cum + c) b_sh = (unsigned)(tid * 8 + j);
            cum += c;
        }
    }
    __syncthreads();
    const unsigned b2 = b_sh;

    unsigned long long s = 0ull;
    unsigned cnt = 0;
#pragma unroll
    for (int j = 0; j < 8; ++j) {
        const unsigned bin = (unsigned)(tid * 8 + j);
        if (bin >= b2) { s += agent_load_u64(&bs2g[bin]); cnt += local2[j]; }
    }
#pragma unroll
    for (int off = 32; off >= 1; off >>= 1) {
        s += __shfl_down(s, off);
        cnt += __shfl_down(cnt, off);
    }
    {
        const int wid = tid >> 6, lane = tid & 63;
        if (lane == 0) { wsum[wid] = s; wcnt[wid] = cnt; }
    }
    __syncthreads();
    if (tid == 0) {
        unsigned long long ts = wsum[0] + wsum[1] + wsum[2] + wsum[3] + agent_load_u64(aboveSum);
        unsigned long long tc = (unsigned long long)(wcnt[0] + wcnt[1] + wcnt[2] + wcnt[3])
                              + (unsigned long long)agent_load_u32(aboveCnt);
        out[0] = (float)(((double)(long long)ts / FIX_SCALE) / (double)tc);
    }
}

extern "C" void kernel_launch(void* const* d_in, const int* in_sizes, int n_in,
                              void* d_out, int out_size, void* d_ws, size_t ws_size,
                              hipStream_t stream) {
    const float* pred = (const float*)d_in[0];
    const int* target = (const int*)d_in[1];
    const int* step = (const int*)d_in[2];
    float* out = (float*)d_out;

    char* ws = (char*)d_ws;
    const size_t LOSS_BYTES = (size_t)NPIX * 4;  // 16 MiB
    float* loss = (float*)ws;
    char* sb = ws + LOSS_BYTES;
    // zeroed state (contiguous 32788 B):
    unsigned* h1 = (unsigned*)(sb);                               // 8192 B
    unsigned* h2 = (unsigned*)(sb + 8192);                        // 8192 B
    unsigned long long* bs2 = (unsigned long long*)(sb + 16384);  // 16384 B
    unsigned long long* aboveSum = (unsigned long long*)(sb + 32768);  // 8 B
    unsigned* aboveCnt = (unsigned*)(sb + 32776);                 // 4 B
    unsigned* ticket = (unsigned*)(sb + 32780);                   // 4 B

    hipMemsetAsync(sb, 0, 32784, stream);
    k_loss_hist<<<1024, 256, 0, stream>>>(pred, target, loss, h1);
    k_hist2_final<<<GRID2, 256, 0, stream>>>(loss, step, h1, h2, bs2,
                                             aboveSum, aboveCnt, ticket, out);
}